// Round 20
// baseline (228.009 us; speedup 1.0000x reference)
//
#include <hip/hip_runtime.h>
#include <hip/hip_bf16.h>

// Problem constants
constexpr int B_ = 8;
constexpr int S_ = 1024;
constexpr int D_ = 768;
constexpr int H_ = 12;
constexpr int F_ = 3072;
constexpr int DH_ = 64;
constexpr int M_ = B_ * S_;       // 8192 rows
constexpr int PSZ = B_ * S_ * D_; // 6291456 elems per q/k/v plane

typedef __bf16 bf16x8 __attribute__((ext_vector_type(8)));
typedef float f32x4 __attribute__((ext_vector_type(4)));
typedef short s16x8 __attribute__((ext_vector_type(8)));
typedef short s16x4 __attribute__((ext_vector_type(4)));

// async global->LDS copy, 16B per lane. LDS dest is wave-uniform base +
// lane*16 (linear). Swizzled layouts via pre-swizzled GLOBAL source (rule #21).
__device__ __forceinline__ void gload_lds16(const __bf16* g, __bf16* l) {
    __builtin_amdgcn_global_load_lds(
        (const __attribute__((address_space(1))) void*)g,
        (__attribute__((address_space(3))) void*)l,
        16, 0, 0);
}

// exact tanh-form GELU via the identity 0.5x(1+tanh(z)) = x * sigmoid(2z)
__device__ __forceinline__ float fast_gelu(float x) {
    float x3 = x * x * x;
    float z = 0.7978845608028654f * x + 0.035677408136300125f * x3;
    float e = __builtin_amdgcn_exp2f(-2.8853900817779268f * z); // exp(-2z)
    return x * __builtin_amdgcn_rcpf(1.0f + e);
}

// ---------------------------------------------------------------------------
// Fused prologue: weight transposes (4 matrices) + LN1, one launch.
// Blocks [0,6912): transpose 32x32 tiles. Blocks [6912,15104): LN1 rows.
// ---------------------------------------------------------------------------
__global__ __launch_bounds__(256) void prep_kernel(
    const float* __restrict__ wqkv, const float* __restrict__ wo,
    const float* __restrict__ w1, const float* __restrict__ w2,
    __bf16* __restrict__ wqkvT, __bf16* __restrict__ woT,
    __bf16* __restrict__ w1T, __bf16* __restrict__ w2T,
    const float* __restrict__ x, const float* __restrict__ ln1g,
    const float* __restrict__ ln1b, __bf16* __restrict__ Hb) {
    __shared__ float t[32][33];
    __shared__ float red[8];
    int id = blockIdx.x;
    if (id < 6912) {
        const float* in;
        __bf16* outp;
        int K, N, loc;
        if (id < 1728)      { in = wqkv; outp = wqkvT; K = 768;  N = 2304; loc = id; }
        else if (id < 2304) { in = wo;   outp = woT;   K = 768;  N = 768;  loc = id - 1728; }
        else if (id < 4608) { in = w1;   outp = w1T;   K = 768;  N = 3072; loc = id - 2304; }
        else                { in = w2;   outp = w2T;   K = 3072; N = 768;  loc = id - 4608; }
        int gx = N / 32;
        int n0 = (loc % gx) * 32, k0 = (loc / gx) * 32;
        int tx = threadIdx.x & 31, ty = threadIdx.x >> 5; // 32x8
#pragma unroll
        for (int i = 0; i < 4; ++i)
            t[ty + i * 8][tx] = in[(size_t)(k0 + ty + i * 8) * N + n0 + tx];
        __syncthreads();
#pragma unroll
        for (int i = 0; i < 4; ++i)
            outp[(size_t)(n0 + ty + i * 8) * K + k0 + tx] = (__bf16)t[tx][ty + i * 8];
    } else {
        int row = id - 6912;
        const float* xr = x + (size_t)row * D_;
        int tid = threadIdx.x;
        float v[3];
        float s = 0.f, s2 = 0.f;
#pragma unroll
        for (int j = 0; j < 3; ++j) {
            v[j] = xr[tid + j * 256];
            s += v[j];
            s2 += v[j] * v[j];
        }
#pragma unroll
        for (int o = 32; o >= 1; o >>= 1) {
            s += __shfl_xor(s, o, 64);
            s2 += __shfl_xor(s2, o, 64);
        }
        int wid = tid >> 6, lane = tid & 63;
        if (lane == 0) { red[wid] = s; red[4 + wid] = s2; }
        __syncthreads();
        s = red[0] + red[1] + red[2] + red[3];
        s2 = red[4] + red[5] + red[6] + red[7];
        float mu = s * (1.0f / D_);
        float var = s2 * (1.0f / D_) - mu * mu;
        float rs = rsqrtf(var + 1e-5f);
        __bf16* orow = Hb + (size_t)row * D_;
#pragma unroll
        for (int j = 0; j < 3; ++j) {
            int i = tid + j * 256;
            orow[i] = (__bf16)((v[j] - mu) * rs * ln1g[i] + ln1b[i]);
        }
    }
}

// ---------------------------------------------------------------------------
// LayerNorm (LN2): one block (256 thr) per row of 768. f32 in -> bf16 out.
// ---------------------------------------------------------------------------
__global__ __launch_bounds__(256) void ln_kernel(const float* __restrict__ x,
                                                 const float* __restrict__ g,
                                                 const float* __restrict__ bb,
                                                 __bf16* __restrict__ out) {
    int row = blockIdx.x;
    const float* xr = x + (size_t)row * D_;
    int tid = threadIdx.x;
    float v[3];
    float s = 0.f, s2 = 0.f;
#pragma unroll
    for (int j = 0; j < 3; ++j) {
        v[j] = xr[tid + j * 256];
        s += v[j];
        s2 += v[j] * v[j];
    }
#pragma unroll
    for (int o = 32; o >= 1; o >>= 1) {
        s += __shfl_xor(s, o, 64);
        s2 += __shfl_xor(s2, o, 64);
    }
    __shared__ float red[8];
    int wid = tid >> 6, lane = tid & 63;
    if (lane == 0) { red[wid] = s; red[4 + wid] = s2; }
    __syncthreads();
    s = red[0] + red[1] + red[2] + red[3];
    s2 = red[4] + red[5] + red[6] + red[7];
    float mu = s * (1.0f / D_);
    float var = s2 * (1.0f / D_) - mu * mu;
    float rs = rsqrtf(var + 1e-5f);
    __bf16* orow = out + (size_t)row * D_;
#pragma unroll
    for (int j = 0; j < 3; ++j) {
        int i = tid + j * 256;
        orow[i] = (__bf16)((v[j] - mu) * rs * g[i] + bb[i]);
    }
}

// ---------------------------------------------------------------------------
// gemm4 (R9-verified K-loop, EXACT): 128x128, BK=64, 256 thr / 4 waves
// (64x64 each), 2 LDS slots (64KB -> 2 blocks/CU). Counted vmcnt(8) (drain
// final tile), barrier order: vmcnt -> bar -> ds_read -> lgkmcnt(0) -> bar
// -> MFMA. XCD block swizzle; XOR LDS swizzle (PMC: 0 conflicts).
// bf16 epilogues (EPI 0/2): per-wave 8KB LDS transpose so each lane stores
// 8x16B contiguous. Slot pc of row lr holds column-group pc^(lr&7); the
// R19 bug stored slot pc's data to column pc — FIXED: data read from slot
// pc = c^(lane&7) is column-group c, stored at dst + c*8.
// ---------------------------------------------------------------------------
template <int EPI>
__global__ __launch_bounds__(256) void gemm4(const __bf16* __restrict__ A,
                                             const __bf16* __restrict__ Bt,
                                             const float* __restrict__ bias,
                                             const float* __restrict__ res,
                                             float* __restrict__ outf,
                                             __bf16* __restrict__ outb,
                                             int M, int N, int K) {
    __shared__ __bf16 lds[2][16384]; // per slot: A[128][64] then B[128][64]

    const int tid = threadIdx.x;
    const int lane = tid & 63, wid = tid >> 6;
    const int wm = wid >> 1, wn = wid & 1;
    const int gx = gridDim.x;
    const int nwg = gx * gridDim.y;
    int flat = blockIdx.y * gx + blockIdx.x;
    flat = (flat & 7) * (nwg >> 3) + (flat >> 3);
    const int bm = (flat / gx) * 128, bn = (flat % gx) * 128;
    const int l15 = lane & 15, l4 = lane >> 4;
    f32x4 acc[4][4] = {};

    const int r8 = tid >> 3; // 0..31
    const int swc = ((tid & 7) ^ (r8 & 7)) * 8;
    const __bf16* ga = A + (size_t)(bm + r8) * K + swc;
    const __bf16* gb = Bt + (size_t)(bn + r8) * K + swc;
    const int NT = K / 64;

    auto stage = [&](int t, int s) {
        const int kt = t * 64;
        __bf16* base = &lds[s][0] + tid * 8;
#pragma unroll
        for (int j = 0; j < 4; ++j)
            gload_lds16(ga + kt + (size_t)j * 32 * K, base + j * 2048);
#pragma unroll
        for (int j = 0; j < 4; ++j)
            gload_lds16(gb + kt + (size_t)j * 32 * K, base + 8192 + j * 2048);
    };

    stage(0, 0);
    for (int t = 0; t < NT; ++t) {
        if (t + 1 < NT) {
            stage(t + 1, (t + 1) & 1);
            asm volatile("s_waitcnt vmcnt(8)" ::: "memory");
        } else {
            asm volatile("s_waitcnt vmcnt(0)" ::: "memory");
        }
        asm volatile("s_barrier" ::: "memory");

        const __bf16* sA = &lds[t & 1][0];
        const __bf16* sB = sA + 8192;
        const int swr = (l15 & 7) * 8;
        bf16x8 a[4][2], b[4][2];
#pragma unroll
        for (int mf = 0; mf < 4; ++mf) {
            int row = wm * 64 + mf * 16 + l15;
#pragma unroll
            for (int ks = 0; ks < 2; ++ks)
                a[mf][ks] = *(const bf16x8*)&sA[row * 64 + ((ks * 32 + l4 * 8) ^ swr)];
        }
#pragma unroll
        for (int nf = 0; nf < 4; ++nf) {
            int row = wn * 64 + nf * 16 + l15;
#pragma unroll
            for (int ks = 0; ks < 2; ++ks)
                b[nf][ks] = *(const bf16x8*)&sB[row * 64 + ((ks * 32 + l4 * 8) ^ swr)];
        }
        asm volatile("s_waitcnt lgkmcnt(0)" ::: "memory");
        asm volatile("s_barrier" ::: "memory");
        __builtin_amdgcn_sched_barrier(0);

        __builtin_amdgcn_s_setprio(1);
#pragma unroll
        for (int ks = 0; ks < 2; ++ks)
#pragma unroll
            for (int mf = 0; mf < 4; ++mf)
#pragma unroll
                for (int nf = 0; nf < 4; ++nf)
                    acc[mf][nf] = __builtin_amdgcn_mfma_f32_16x16x32_bf16(
                        a[mf][ks], b[nf][ks], acc[mf][nf], 0, 0, 0);
        __builtin_amdgcn_s_setprio(0);
    }

    if constexpr (EPI == 0 || EPI == 2) {
        // per-wave 64x64 bf16 transpose buffer (8KB); chunk-XOR placement.
        __bf16* wbuf = &lds[0][0] + wid * 4096;
#pragma unroll
        for (int nf = 0; nf < 4; ++nf) {
            float bv = bias[bn + wn * 64 + nf * 16 + l15];
#pragma unroll
            for (int mf = 0; mf < 4; ++mf) {
#pragma unroll
                for (int r = 0; r < 4; ++r) {
                    int lr = mf * 16 + l4 * 4 + r;  // 0..63 local row
                    int lc = nf * 16 + l15;         // 0..63 local col
                    float val = acc[mf][nf][r] + bv;
                    if constexpr (EPI == 2) val = fast_gelu(val);
                    int chunk = (lc >> 3) ^ (lr & 7);
                    wbuf[lr * 64 + chunk * 8 + (lc & 7)] = (__bf16)val;
                }
            }
        }
        asm volatile("s_waitcnt lgkmcnt(0)" ::: "memory"); // own writes landed
        // lane reads its row back; slot pc holds column-group pc^(lane&7)=c
        int m = bm + wm * 64 + lane;
        int n0 = bn + wn * 64; // 64-aligned span
        __bf16* dst;
        if constexpr (EPI == 0) {
            int part = n0 / 768;
            int n7 = n0 - part * 768;
            int head = n7 >> 6; // dh0 == 0 (64-aligned within head)
            dst = outb + (size_t)part * PSZ +
                  (((size_t)(m >> 10) * H_ + head) * S_ + (m & 1023)) * DH_;
        } else {
            dst = outb + (size_t)m * N + n0;
        }
#pragma unroll
        for (int c = 0; c < 8; ++c) {
            int pc = c ^ (lane & 7); // read address slot
            bf16x8 v = *(const bf16x8*)&wbuf[lane * 64 + pc * 8];
            *(s16x8*)(dst + (c << 3)) = *(const s16x8*)&v; // data IS col-group c
        }
    } else {
#pragma unroll
        for (int mf = 0; mf < 4; ++mf) {
#pragma unroll
            for (int nf = 0; nf < 4; ++nf) {
#pragma unroll
                for (int r = 0; r < 4; ++r) {
                    int m = bm + wm * 64 + mf * 16 + l4 * 4 + r;
                    int n = bn + wn * 64 + nf * 16 + l15;
                    float val = acc[mf][nf][r] + bias[n];
                    outf[(size_t)m * N + n] = val + res[(size_t)m * N + n];
                }
            }
        }
    }
    (void)res; (void)outf; (void)outb;
}

// ---------------------------------------------------------------------------
// Quad2 attention (R9-verified structure, plain block mapping)
// ---------------------------------------------------------------------------
__global__ __launch_bounds__(256) void attn_kernel(const __bf16* __restrict__ qg,
                                                   const __bf16* __restrict__ kg,
                                                   const __bf16* __restrict__ vg,
                                                   __bf16* __restrict__ ctx) {
    __shared__ __bf16 Ks[64][72];
    __shared__ __bf16 Vt[64][72];
    __shared__ __bf16 Pw[4][32][72];
    __shared__ float den_l[4][32];
    int tid = threadIdx.x, lane = tid & 63, wid = tid >> 6;
    int l15 = lane & 15, l4 = lane >> 4;
    int bh = blockIdx.x >> 3, qt = blockIdx.x & 7;
    int q0 = qt * 128;
    const __bf16* qbase = qg + (size_t)bh * S_ * DH_;
    const __bf16* kbase = kg + (size_t)bh * S_ * DH_;
    const __bf16* vbase = vg + (size_t)bh * S_ * DH_;

    int wq0 = q0 + wid * 32;
    bf16x8 qf[2][2];
#pragma unroll
    for (int qi = 0; qi < 2; ++qi)
#pragma unroll
        for (int ks = 0; ks < 2; ++ks)
            qf[qi][ks] = *(const bf16x8*)(qbase + (size_t)(wq0 + qi * 16 + l15) * DH_ +
                                          ks * 32 + l4 * 8);

    f32x4 oacc[2][4] = {};
    float den[2] = {0.f, 0.f};
    const float scale = 0.125f; // 1/sqrt(64)

    for (int k0 = 0; k0 < S_; k0 += 64) {
        {
            int key = tid >> 2, dc = (tid & 3) * 16;
            *(s16x8*)&Ks[key][dc] =
                *(const s16x8*)(kbase + (size_t)(k0 + key) * DH_ + dc);
            *(s16x8*)&Ks[key][dc + 8] =
                *(const s16x8*)(kbase + (size_t)(k0 + key) * DH_ + dc + 8);
            int vkey = tid & 63, dg = (tid >> 6) * 16;
            s16x8 v0 = *(const s16x8*)(vbase + (size_t)(k0 + vkey) * DH_ + dg);
            s16x8 v1 = *(const s16x8*)(vbase + (size_t)(k0 + vkey) * DH_ + dg + 8);
#pragma unroll
            for (int e = 0; e < 8; ++e) {
                Vt[dg + e][vkey] = ((const __bf16*)&v0)[e];
                Vt[dg + 8 + e][vkey] = ((const __bf16*)&v1)[e];
            }
        }
        __syncthreads();

        bf16x8 kf[4][2];
#pragma unroll
        for (int kfi = 0; kfi < 4; ++kfi)
#pragma unroll
            for (int ks = 0; ks < 2; ++ks)
                kf[kfi][ks] = *(const bf16x8*)&Ks[kfi * 16 + l15][ks * 32 + l4 * 8];

#pragma unroll
        for (int qi = 0; qi < 2; ++qi) {
#pragma unroll
            for (int kfi = 0; kfi < 4; ++kfi) {
                f32x4 sa = {};
                sa = __builtin_amdgcn_mfma_f32_16x16x32_bf16(kf[kfi][0], qf[qi][0], sa, 0, 0, 0);
                sa = __builtin_amdgcn_mfma_f32_16x16x32_bf16(kf[kfi][1], qf[qi][1], sa, 0, 0, 0);
                __bf16 pk[4];
#pragma unroll
                for (int r = 0; r < 4; ++r) {
                    float p = sa[r] * scale + 5.0f;
                    p = p * p;
                    den[qi] += p;
                    pk[r] = (__bf16)p;
                }
                *(s16x4*)&Pw[wid][qi * 16 + l15][kfi * 16 + l4 * 4] =
                    *(const s16x4*)pk;
            }
        }

#pragma unroll
        for (int mf = 0; mf < 2; ++mf) {
#pragma unroll
            for (int ks = 0; ks < 2; ++ks) {
                bf16x8 pa = *(const bf16x8*)&Pw[wid][mf * 16 + l15][ks * 32 + l4 * 8];
#pragma unroll
                for (int nf = 0; nf < 4; ++nf) {
                    bf16x8 vb = *(const bf16x8*)&Vt[nf * 16 + l15][ks * 32 + l4 * 8];
                    oacc[mf][nf] = __builtin_amdgcn_mfma_f32_16x16x32_bf16(
                        pa, vb, oacc[mf][nf], 0, 0, 0);
                }
            }
        }
        __syncthreads();
    }

#pragma unroll
    for (int qi = 0; qi < 2; ++qi) {
        den[qi] += __shfl_xor(den[qi], 16, 64);
        den[qi] += __shfl_xor(den[qi], 32, 64);
    }
    if (lane < 16) {
        den_l[wid][lane] = den[0];
        den_l[wid][16 + lane] = den[1];
    }
    __syncthreads();

    int b_ = bh / H_, h_ = bh - b_ * H_;
#pragma unroll
    for (int mf = 0; mf < 2; ++mf)
#pragma unroll
        for (int nf = 0; nf < 4; ++nf) {
#pragma unroll
            for (int r = 0; r < 4; ++r) {
                int qrow = mf * 16 + l4 * 4 + r;
                int dcol = nf * 16 + l15;
                float val = oacc[mf][nf][r] *
                            __builtin_amdgcn_rcpf(den_l[wid][qrow]);
                int sI = q0 + wid * 32 + qrow;
                ctx[((size_t)b_ * S_ + sI) * D_ + h_ * DH_ + dcol] = (__bf16)val;
            }
        }
}

// ---------------------------------------------------------------------------
extern "C" void kernel_launch(void* const* d_in, const int* in_sizes, int n_in,
                              void* d_out, int out_size, void* d_ws, size_t ws_size,
                              hipStream_t stream) {
    const float* x    = (const float*)d_in[0];
    const float* wqkv = (const float*)d_in[1];
    const float* bqkv = (const float*)d_in[2];
    const float* wo   = (const float*)d_in[3];
    const float* bo   = (const float*)d_in[4];
    const float* ln1g = (const float*)d_in[5];
    const float* ln1b = (const float*)d_in[6];
    const float* w1   = (const float*)d_in[7];
    const float* b1   = (const float*)d_in[8];
    const float* w2   = (const float*)d_in[9];
    const float* b2   = (const float*)d_in[10];
    const float* ln2g = (const float*)d_in[11];
    const float* ln2b = (const float*)d_in[12];
    float* out = (float*)d_out;

    char* ws = (char*)d_ws;
    size_t off = 0;
    auto alloc = [&](size_t bytes) {
        void* p = ws + off;
        off += (bytes + 255) & ~(size_t)255;
        return p;
    };
    __bf16* wqkvT = (__bf16*)alloc((size_t)(3 * D_) * D_ * 2);
    __bf16* woT   = (__bf16*)alloc((size_t)D_ * D_ * 2);
    __bf16* w1T   = (__bf16*)alloc((size_t)F_ * D_ * 2);
    __bf16* w2T   = (__bf16*)alloc((size_t)D_ * F_ * 2);
    float*  X2    = (float*)alloc((size_t)M_ * D_ * 4);
    __bf16* Hb    = (__bf16*)alloc((size_t)M_ * D_ * 2);
    __bf16* Q3    = (__bf16*)alloc((size_t)4 * PSZ * 2); // q,k,v,ctx ; reused as act
    __bf16* Kb = Q3 + (size_t)PSZ;
    __bf16* Vb = Q3 + (size_t)2 * PSZ;
    __bf16* Cx = Q3 + (size_t)3 * PSZ;

    // 1. fused: all weight transposes + LN1 (independent jobs, one launch)
    prep_kernel<<<6912 + M_, 256, 0, stream>>>(wqkv, wo, w1, w2,
                                               wqkvT, woT, w1T, w2T,
                                               x, ln1g, ln1b, Hb);
    // 2. QKV GEMM (scatter to q/k/v planes)
    gemm4<0><<<dim3((3 * D_) / 128, M_ / 128), 256, 0, stream>>>(
        Hb, wqkvT, bqkv, nullptr, nullptr, Q3, M_, 3 * D_, D_);
    // 3. attention -> ctx
    attn_kernel<<<B_ * H_ * (S_ / 128), 256, 0, stream>>>(Q3, Kb, Vb, Cx);
    // 4. output projection + residual -> X2 (f32)
    gemm4<1><<<dim3(D_ / 128, M_ / 128), 256, 0, stream>>>(
        Cx, woT, bo, x, X2, nullptr, M_, D_, D_);
    // 5. LN2
    ln_kernel<<<M_, 256, 0, stream>>>(X2, ln2g, ln2b, Hb);
    // 6. FFN1 + GELU -> act (reuses q/k/v/ctx region)
    gemm4<2><<<dim3(F_ / 128, M_ / 128), 256, 0, stream>>>(
        Hb, w1T, b1, nullptr, nullptr, Q3, M_, F_, D_);
    // 7. FFN2 + residual -> out
    gemm4<1><<<dim3(D_ / 128, M_ / 128), 256, 0, stream>>>(
        Q3, w2T, b2, X2, out, nullptr, M_, D_, F_);
    (void)in_sizes; (void)n_in; (void)out_size; (void)ws_size;
}

// Round 21
// 212.183 us; speedup vs baseline: 1.0746x; 1.0746x over previous
//
#include <hip/hip_runtime.h>
#include <hip/hip_bf16.h>

// Problem constants
constexpr int B_ = 8;
constexpr int S_ = 1024;
constexpr int D_ = 768;
constexpr int H_ = 12;
constexpr int F_ = 3072;
constexpr int DH_ = 64;
constexpr int M_ = B_ * S_;       // 8192 rows
constexpr int PSZ = B_ * S_ * D_; // 6291456 elems per q/k/v plane

typedef __bf16 bf16x8 __attribute__((ext_vector_type(8)));
typedef float f32x4 __attribute__((ext_vector_type(4)));
typedef short s16x8 __attribute__((ext_vector_type(8)));
typedef short s16x4 __attribute__((ext_vector_type(4)));

// async global->LDS copy, 16B per lane. LDS dest is wave-uniform base +
// lane*16 (linear). Swizzled layouts via pre-swizzled GLOBAL source (rule #21).
__device__ __forceinline__ void gload_lds16(const __bf16* g, __bf16* l) {
    __builtin_amdgcn_global_load_lds(
        (const __attribute__((address_space(1))) void*)g,
        (__attribute__((address_space(3))) void*)l,
        16, 0, 0);
}

// exact tanh-form GELU via the identity 0.5x(1+tanh(z)) = x * sigmoid(2z)
__device__ __forceinline__ float fast_gelu(float x) {
    float x3 = x * x * x;
    float z = 0.7978845608028654f * x + 0.035677408136300125f * x3;
    float e = __builtin_amdgcn_exp2f(-2.8853900817779268f * z); // exp(-2z)
    return x * __builtin_amdgcn_rcpf(1.0f + e);
}

// ---------------------------------------------------------------------------
// Fused prologue: weight transposes (4 matrices) + LN1, one launch.
// Blocks [0,6912): transpose 32x32 tiles. Blocks [6912,15104): LN1 rows.
// ---------------------------------------------------------------------------
__global__ __launch_bounds__(256) void prep_kernel(
    const float* __restrict__ wqkv, const float* __restrict__ wo,
    const float* __restrict__ w1, const float* __restrict__ w2,
    __bf16* __restrict__ wqkvT, __bf16* __restrict__ woT,
    __bf16* __restrict__ w1T, __bf16* __restrict__ w2T,
    const float* __restrict__ x, const float* __restrict__ ln1g,
    const float* __restrict__ ln1b, __bf16* __restrict__ Hb) {
    __shared__ float t[32][33];
    __shared__ float red[8];
    int id = blockIdx.x;
    if (id < 6912) {
        const float* in;
        __bf16* outp;
        int K, N, loc;
        if (id < 1728)      { in = wqkv; outp = wqkvT; K = 768;  N = 2304; loc = id; }
        else if (id < 2304) { in = wo;   outp = woT;   K = 768;  N = 768;  loc = id - 1728; }
        else if (id < 4608) { in = w1;   outp = w1T;   K = 768;  N = 3072; loc = id - 2304; }
        else                { in = w2;   outp = w2T;   K = 3072; N = 768;  loc = id - 4608; }
        int gx = N / 32;
        int n0 = (loc % gx) * 32, k0 = (loc / gx) * 32;
        int tx = threadIdx.x & 31, ty = threadIdx.x >> 5; // 32x8
#pragma unroll
        for (int i = 0; i < 4; ++i)
            t[ty + i * 8][tx] = in[(size_t)(k0 + ty + i * 8) * N + n0 + tx];
        __syncthreads();
#pragma unroll
        for (int i = 0; i < 4; ++i)
            outp[(size_t)(n0 + ty + i * 8) * K + k0 + tx] = (__bf16)t[tx][ty + i * 8];
    } else {
        int row = id - 6912;
        const float* xr = x + (size_t)row * D_;
        int tid = threadIdx.x;
        float v[3];
        float s = 0.f, s2 = 0.f;
#pragma unroll
        for (int j = 0; j < 3; ++j) {
            v[j] = xr[tid + j * 256];
            s += v[j];
            s2 += v[j] * v[j];
        }
#pragma unroll
        for (int o = 32; o >= 1; o >>= 1) {
            s += __shfl_xor(s, o, 64);
            s2 += __shfl_xor(s2, o, 64);
        }
        int wid = tid >> 6, lane = tid & 63;
        if (lane == 0) { red[wid] = s; red[4 + wid] = s2; }
        __syncthreads();
        s = red[0] + red[1] + red[2] + red[3];
        s2 = red[4] + red[5] + red[6] + red[7];
        float mu = s * (1.0f / D_);
        float var = s2 * (1.0f / D_) - mu * mu;
        float rs = rsqrtf(var + 1e-5f);
        __bf16* orow = Hb + (size_t)row * D_;
#pragma unroll
        for (int j = 0; j < 3; ++j) {
            int i = tid + j * 256;
            orow[i] = (__bf16)((v[j] - mu) * rs * ln1g[i] + ln1b[i]);
        }
    }
}

// ---------------------------------------------------------------------------
// LayerNorm (LN2): one block (256 thr) per row of 768. f32 in -> bf16 out.
// ---------------------------------------------------------------------------
__global__ __launch_bounds__(256) void ln_kernel(const float* __restrict__ x,
                                                 const float* __restrict__ g,
                                                 const float* __restrict__ bb,
                                                 __bf16* __restrict__ out) {
    int row = blockIdx.x;
    const float* xr = x + (size_t)row * D_;
    int tid = threadIdx.x;
    float v[3];
    float s = 0.f, s2 = 0.f;
#pragma unroll
    for (int j = 0; j < 3; ++j) {
        v[j] = xr[tid + j * 256];
        s += v[j];
        s2 += v[j] * v[j];
    }
#pragma unroll
    for (int o = 32; o >= 1; o >>= 1) {
        s += __shfl_xor(s, o, 64);
        s2 += __shfl_xor(s2, o, 64);
    }
    __shared__ float red[8];
    int wid = tid >> 6, lane = tid & 63;
    if (lane == 0) { red[wid] = s; red[4 + wid] = s2; }
    __syncthreads();
    s = red[0] + red[1] + red[2] + red[3];
    s2 = red[4] + red[5] + red[6] + red[7];
    float mu = s * (1.0f / D_);
    float var = s2 * (1.0f / D_) - mu * mu;
    float rs = rsqrtf(var + 1e-5f);
    __bf16* orow = out + (size_t)row * D_;
#pragma unroll
    for (int j = 0; j < 3; ++j) {
        int i = tid + j * 256;
        orow[i] = (__bf16)((v[j] - mu) * rs * g[i] + bb[i]);
    }
}

// ---------------------------------------------------------------------------
// gemm4 (R9-verified, EXACT — the twice-reproduced 212µs configuration):
// 128x128, BK=64, 256 thr / 4 waves (64x64 each), 2 LDS slots (64KB ->
// 2 blocks/CU). Counted vmcnt(8) (drain final tile), barrier order:
// vmcnt -> bar -> ds_read -> lgkmcnt(0) -> bar -> MFMA. XCD block swizzle;
// XOR LDS swizzle (PMC: 0 conflicts). Scalar epilogue stores (coalesce
// across quarter-wave into 128B transactions; R20 proved the LDS-transpose
// "vectorization" costs more than it saves).
// EPI 0: scatter bf16 to q/k/v planes   EPI 1: f32 + bias + residual
// EPI 2: bf16 gelu(x+bias)
// ---------------------------------------------------------------------------
template <int EPI>
__global__ __launch_bounds__(256) void gemm4(const __bf16* __restrict__ A,
                                             const __bf16* __restrict__ Bt,
                                             const float* __restrict__ bias,
                                             const float* __restrict__ res,
                                             float* __restrict__ outf,
                                             __bf16* __restrict__ outb,
                                             int M, int N, int K) {
    __shared__ __bf16 lds[2][16384]; // per slot: A[128][64] then B[128][64]

    const int tid = threadIdx.x;
    const int lane = tid & 63, wid = tid >> 6;
    const int wm = wid >> 1, wn = wid & 1;
    const int gx = gridDim.x;
    const int nwg = gx * gridDim.y;
    int flat = blockIdx.y * gx + blockIdx.x;
    flat = (flat & 7) * (nwg >> 3) + (flat >> 3);
    const int bm = (flat / gx) * 128, bn = (flat % gx) * 128;
    const int l15 = lane & 15, l4 = lane >> 4;
    f32x4 acc[4][4] = {};

    const int r8 = tid >> 3; // 0..31
    const int swc = ((tid & 7) ^ (r8 & 7)) * 8;
    const __bf16* ga = A + (size_t)(bm + r8) * K + swc;
    const __bf16* gb = Bt + (size_t)(bn + r8) * K + swc;
    const int NT = K / 64;

    auto stage = [&](int t, int s) {
        const int kt = t * 64;
        __bf16* base = &lds[s][0] + tid * 8;
#pragma unroll
        for (int j = 0; j < 4; ++j)
            gload_lds16(ga + kt + (size_t)j * 32 * K, base + j * 2048);
#pragma unroll
        for (int j = 0; j < 4; ++j)
            gload_lds16(gb + kt + (size_t)j * 32 * K, base + 8192 + j * 2048);
    };

    stage(0, 0);
    for (int t = 0; t < NT; ++t) {
        if (t + 1 < NT) {
            stage(t + 1, (t + 1) & 1);
            asm volatile("s_waitcnt vmcnt(8)" ::: "memory");
        } else {
            asm volatile("s_waitcnt vmcnt(0)" ::: "memory");
        }
        asm volatile("s_barrier" ::: "memory");

        const __bf16* sA = &lds[t & 1][0];
        const __bf16* sB = sA + 8192;
        const int swr = (l15 & 7) * 8;
        bf16x8 a[4][2], b[4][2];
#pragma unroll
        for (int mf = 0; mf < 4; ++mf) {
            int row = wm * 64 + mf * 16 + l15;
#pragma unroll
            for (int ks = 0; ks < 2; ++ks)
                a[mf][ks] = *(const bf16x8*)&sA[row * 64 + ((ks * 32 + l4 * 8) ^ swr)];
        }
#pragma unroll
        for (int nf = 0; nf < 4; ++nf) {
            int row = wn * 64 + nf * 16 + l15;
#pragma unroll
            for (int ks = 0; ks < 2; ++ks)
                b[nf][ks] = *(const bf16x8*)&sB[row * 64 + ((ks * 32 + l4 * 8) ^ swr)];
        }
        asm volatile("s_waitcnt lgkmcnt(0)" ::: "memory");
        asm volatile("s_barrier" ::: "memory");
        __builtin_amdgcn_sched_barrier(0);

        __builtin_amdgcn_s_setprio(1);
#pragma unroll
        for (int ks = 0; ks < 2; ++ks)
#pragma unroll
            for (int mf = 0; mf < 4; ++mf)
#pragma unroll
                for (int nf = 0; nf < 4; ++nf)
                    acc[mf][nf] = __builtin_amdgcn_mfma_f32_16x16x32_bf16(
                        a[mf][ks], b[nf][ks], acc[mf][nf], 0, 0, 0);
        __builtin_amdgcn_s_setprio(0);
    }

    if constexpr (EPI == 0) {
#pragma unroll
        for (int nf = 0; nf < 4; ++nf) {
            int n = bn + wn * 64 + nf * 16 + l15;
            int part = n / 768;
            int n7 = n - part * 768;
            float bv = bias[n];
            size_t obase = (size_t)part * PSZ + (size_t)(n7 >> 6) * (S_ * DH_) + (n7 & 63);
#pragma unroll
            for (int mf = 0; mf < 4; ++mf) {
                int m0 = bm + wm * 64 + mf * 16 + l4 * 4;
                size_t rb = obase + (size_t)(m0 >> 10) * ((size_t)H_ * S_ * DH_) +
                            (size_t)(m0 & 1023) * DH_;
#pragma unroll
                for (int r = 0; r < 4; ++r)
                    outb[rb + (size_t)r * DH_] = (__bf16)(acc[mf][nf][r] + bv);
            }
        }
    } else {
#pragma unroll
        for (int mf = 0; mf < 4; ++mf) {
#pragma unroll
            for (int nf = 0; nf < 4; ++nf) {
#pragma unroll
                for (int r = 0; r < 4; ++r) {
                    int m = bm + wm * 64 + mf * 16 + l4 * 4 + r;
                    int n = bn + wn * 64 + nf * 16 + l15;
                    float val = acc[mf][nf][r] + bias[n];
                    if constexpr (EPI == 1) {
                        outf[(size_t)m * N + n] = val + res[(size_t)m * N + n];
                    } else {
                        outb[(size_t)m * N + n] = (__bf16)fast_gelu(val);
                    }
                }
            }
        }
    }
    (void)res; (void)outf;
}

// ---------------------------------------------------------------------------
// Quad2 attention (R9-verified structure, plain block mapping)
// ---------------------------------------------------------------------------
__global__ __launch_bounds__(256) void attn_kernel(const __bf16* __restrict__ qg,
                                                   const __bf16* __restrict__ kg,
                                                   const __bf16* __restrict__ vg,
                                                   __bf16* __restrict__ ctx) {
    __shared__ __bf16 Ks[64][72];
    __shared__ __bf16 Vt[64][72];
    __shared__ __bf16 Pw[4][32][72];
    __shared__ float den_l[4][32];
    int tid = threadIdx.x, lane = tid & 63, wid = tid >> 6;
    int l15 = lane & 15, l4 = lane >> 4;
    int bh = blockIdx.x >> 3, qt = blockIdx.x & 7;
    int q0 = qt * 128;
    const __bf16* qbase = qg + (size_t)bh * S_ * DH_;
    const __bf16* kbase = kg + (size_t)bh * S_ * DH_;
    const __bf16* vbase = vg + (size_t)bh * S_ * DH_;

    int wq0 = q0 + wid * 32;
    bf16x8 qf[2][2];
#pragma unroll
    for (int qi = 0; qi < 2; ++qi)
#pragma unroll
        for (int ks = 0; ks < 2; ++ks)
            qf[qi][ks] = *(const bf16x8*)(qbase + (size_t)(wq0 + qi * 16 + l15) * DH_ +
                                          ks * 32 + l4 * 8);

    f32x4 oacc[2][4] = {};
    float den[2] = {0.f, 0.f};
    const float scale = 0.125f; // 1/sqrt(64)

    for (int k0 = 0; k0 < S_; k0 += 64) {
        {
            int key = tid >> 2, dc = (tid & 3) * 16;
            *(s16x8*)&Ks[key][dc] =
                *(const s16x8*)(kbase + (size_t)(k0 + key) * DH_ + dc);
            *(s16x8*)&Ks[key][dc + 8] =
                *(const s16x8*)(kbase + (size_t)(k0 + key) * DH_ + dc + 8);
            int vkey = tid & 63, dg = (tid >> 6) * 16;
            s16x8 v0 = *(const s16x8*)(vbase + (size_t)(k0 + vkey) * DH_ + dg);
            s16x8 v1 = *(const s16x8*)(vbase + (size_t)(k0 + vkey) * DH_ + dg + 8);
#pragma unroll
            for (int e = 0; e < 8; ++e) {
                Vt[dg + e][vkey] = ((const __bf16*)&v0)[e];
                Vt[dg + 8 + e][vkey] = ((const __bf16*)&v1)[e];
            }
        }
        __syncthreads();

        bf16x8 kf[4][2];
#pragma unroll
        for (int kfi = 0; kfi < 4; ++kfi)
#pragma unroll
            for (int ks = 0; ks < 2; ++ks)
                kf[kfi][ks] = *(const bf16x8*)&Ks[kfi * 16 + l15][ks * 32 + l4 * 8];

#pragma unroll
        for (int qi = 0; qi < 2; ++qi) {
#pragma unroll
            for (int kfi = 0; kfi < 4; ++kfi) {
                f32x4 sa = {};
                sa = __builtin_amdgcn_mfma_f32_16x16x32_bf16(kf[kfi][0], qf[qi][0], sa, 0, 0, 0);
                sa = __builtin_amdgcn_mfma_f32_16x16x32_bf16(kf[kfi][1], qf[qi][1], sa, 0, 0, 0);
                __bf16 pk[4];
#pragma unroll
                for (int r = 0; r < 4; ++r) {
                    float p = sa[r] * scale + 5.0f;
                    p = p * p;
                    den[qi] += p;
                    pk[r] = (__bf16)p;
                }
                *(s16x4*)&Pw[wid][qi * 16 + l15][kfi * 16 + l4 * 4] =
                    *(const s16x4*)pk;
            }
        }

#pragma unroll
        for (int mf = 0; mf < 2; ++mf) {
#pragma unroll
            for (int ks = 0; ks < 2; ++ks) {
                bf16x8 pa = *(const bf16x8*)&Pw[wid][mf * 16 + l15][ks * 32 + l4 * 8];
#pragma unroll
                for (int nf = 0; nf < 4; ++nf) {
                    bf16x8 vb = *(const bf16x8*)&Vt[nf * 16 + l15][ks * 32 + l4 * 8];
                    oacc[mf][nf] = __builtin_amdgcn_mfma_f32_16x16x32_bf16(
                        pa, vb, oacc[mf][nf], 0, 0, 0);
                }
            }
        }
        __syncthreads();
    }

#pragma unroll
    for (int qi = 0; qi < 2; ++qi) {
        den[qi] += __shfl_xor(den[qi], 16, 64);
        den[qi] += __shfl_xor(den[qi], 32, 64);
    }
    if (lane < 16) {
        den_l[wid][lane] = den[0];
        den_l[wid][16 + lane] = den[1];
    }
    __syncthreads();

    int b_ = bh / H_, h_ = bh - b_ * H_;
#pragma unroll
    for (int mf = 0; mf < 2; ++mf)
#pragma unroll
        for (int nf = 0; nf < 4; ++nf) {
#pragma unroll
            for (int r = 0; r < 4; ++r) {
                int qrow = mf * 16 + l4 * 4 + r;
                int dcol = nf * 16 + l15;
                float val = oacc[mf][nf][r] *
                            __builtin_amdgcn_rcpf(den_l[wid][qrow]);
                int sI = q0 + wid * 32 + qrow;
                ctx[((size_t)b_ * S_ + sI) * D_ + h_ * DH_ + dcol] = (__bf16)val;
            }
        }
}

// ---------------------------------------------------------------------------
extern "C" void kernel_launch(void* const* d_in, const int* in_sizes, int n_in,
                              void* d_out, int out_size, void* d_ws, size_t ws_size,
                              hipStream_t stream) {
    const float* x    = (const float*)d_in[0];
    const float* wqkv = (const float*)d_in[1];
    const float* bqkv = (const float*)d_in[2];
    const float* wo   = (const float*)d_in[3];
    const float* bo   = (const float*)d_in[4];
    const float* ln1g = (const float*)d_in[5];
    const float* ln1b = (const float*)d_in[6];
    const float* w1   = (const float*)d_in[7];
    const float* b1   = (const float*)d_in[8];
    const float* w2   = (const float*)d_in[9];
    const float* b2   = (const float*)d_in[10];
    const float* ln2g = (const float*)d_in[11];
    const float* ln2b = (const float*)d_in[12];
    float* out = (float*)d_out;

    char* ws = (char*)d_ws;
    size_t off = 0;
    auto alloc = [&](size_t bytes) {
        void* p = ws + off;
        off += (bytes + 255) & ~(size_t)255;
        return p;
    };
    __bf16* wqkvT = (__bf16*)alloc((size_t)(3 * D_) * D_ * 2);
    __bf16* woT   = (__bf16*)alloc((size_t)D_ * D_ * 2);
    __bf16* w1T   = (__bf16*)alloc((size_t)F_ * D_ * 2);
    __bf16* w2T   = (__bf16*)alloc((size_t)D_ * F_ * 2);
    float*  X2    = (float*)alloc((size_t)M_ * D_ * 4);
    __bf16* Hb    = (__bf16*)alloc((size_t)M_ * D_ * 2);
    __bf16* Q3    = (__bf16*)alloc((size_t)4 * PSZ * 2); // q,k,v,ctx ; reused as act
    __bf16* Kb = Q3 + (size_t)PSZ;
    __bf16* Vb = Q3 + (size_t)2 * PSZ;
    __bf16* Cx = Q3 + (size_t)3 * PSZ;

    // 1. fused: all weight transposes + LN1 (independent jobs, one launch)
    prep_kernel<<<6912 + M_, 256, 0, stream>>>(wqkv, wo, w1, w2,
                                               wqkvT, woT, w1T, w2T,
                                               x, ln1g, ln1b, Hb);
    // 2. QKV GEMM (scatter to q/k/v planes)
    gemm4<0><<<dim3((3 * D_) / 128, M_ / 128), 256, 0, stream>>>(
        Hb, wqkvT, bqkv, nullptr, nullptr, Q3, M_, 3 * D_, D_);
    // 3. attention -> ctx
    attn_kernel<<<B_ * H_ * (S_ / 128), 256, 0, stream>>>(Q3, Kb, Vb, Cx);
    // 4. output projection + residual -> X2 (f32)
    gemm4<1><<<dim3(D_ / 128, M_ / 128), 256, 0, stream>>>(
        Cx, woT, bo, x, X2, nullptr, M_, D_, D_);
    // 5. LN2
    ln_kernel<<<M_, 256, 0, stream>>>(X2, ln2g, ln2b, Hb);
    // 6. FFN1 + GELU -> act (reuses q/k/v/ctx region)
    gemm4<2><<<dim3(F_ / 128, M_ / 128), 256, 0, stream>>>(
        Hb, w1T, b1, nullptr, nullptr, Q3, M_, F_, D_);
    // 7. FFN2 + residual -> out
    gemm4<1><<<dim3(D_ / 128, M_ / 128), 256, 0, stream>>>(
        Q3, w2T, b2, X2, out, nullptr, M_, D_, F_);
    (void)in_sizes; (void)n_in; (void)out_size; (void)ws_size;
}